// Round 29
// baseline (63.779 us; speedup 1.0000x reference)
//
#include <hip/hip_runtime.h>
#include <stdint.h>

#define IC 128
#define OC 256
#define RR 64
#define CCOLS 64
#define HO 62
#define WO 62
#define NB 16

// Fragment-major dense bf16 weights: W9Tf[chunk][g][lane][16B],
// chunk = kp*8+ck (72), g = oc>>5 (8), lane = (oc&31)+32*khalf.
#define W9T_BYTES (9 * OC * IC * 2)   // 589824
#define W9T_PAD   131072              // zero pad: junk tail A-loads land here
#define CHUNK_STRIDE 8192
// B LDS layout: [krow 6][octet 16][x 64][16B] = 98304 B + 4 KB pad for the
// rolled loop's junk tail B-reads.
#define LDS_TOTAL 102400

typedef __bf16 bf16x8 __attribute__((ext_vector_type(8)));
typedef float f32x16 __attribute__((ext_vector_type(16)));

__device__ __forceinline__ unsigned short f2bf(float f) {
    unsigned u = __builtin_bit_cast(unsigned, f);
    u += 0x7FFFu + ((u >> 16) & 1u);   // round-to-nearest-even
    return (unsigned short)(u >> 16);
}

// prep: blocks 0..OC-1 scatter weights; block OC densifies the bias.
__global__ void prep_weights(const float* __restrict__ wv,
                             const int* __restrict__ iwi,
                             const int* __restrict__ flen,
                             const int* __restrict__ sp,
                             unsigned char* __restrict__ W9Tf,
                             const int* __restrict__ bias_index,
                             const float* __restrict__ bias_value,
                             float* __restrict__ bias_dense, int nbias) {
    if (blockIdx.x == OC) {
        int t = threadIdx.x;
        if (t < OC) bias_dense[t] = 0.f;
        __syncthreads();
        if (t < nbias) atomicAdd(&bias_dense[bias_index[t]], bias_value[t]);
        return;
    }
    const int oc = blockIdx.x;
    const int s = sp[oc];
    const int n = flen[oc];
    const int g = oc >> 5;
    for (int t = threadIdx.x; t < n; t += blockDim.x) {
        const int ix = iwi[s + t];          // c*4096 + ky*64 + kx
        const int c = ix >> 12;
        const int rem = ix & 4095;
        const int ky = rem >> 6, kx = rem & 63;
        const int kp = ky * 3 + kx;
        const int ck = c >> 4;
        const int khalf = (c >> 3) & 1;
        const int lane = (oc & 31) + (khalf << 5);
        const size_t off = (size_t)(kp * 8 + ck) * CHUNK_STRIDE +
                           g * 1024 + lane * 16 + (c & 7) * 2;
        *(unsigned short*)(W9Tf + off) = f2bf(wv[s + t]);
    }
}

// One K-chunk step, 4 chains (2 oc x 2 n x 1 y). A-slot = CK&1 (2-deep
// rotation, uniform over the 8-step group); B sets alternate X/Y. Steady
// vmcnt(2) [chunk k+1's 2 loads may remain] / lgkmcnt(2) [next chunk's 2
// reads remain]. Junk tail prefetches (last group) land in zero pad (A)
// and LDS pad (B); drained after the loop with all targets tied.
#define KSTEP_L(CK, AV0, AV1, C0, C1, N0, N1, PB0, PB1, POFF)                 \
  {                                                                           \
    asm volatile("ds_read_b128 %0, %1 offset:%c2" : "=v"(N0) : "v"(PB0), "i"(POFF)); \
    asm volatile("ds_read_b128 %0, %1 offset:%c2" : "=v"(N1) : "v"(PB1), "i"((POFF) + 512)); \
    asm volatile("s_waitcnt vmcnt(2) lgkmcnt(2)"                              \
                 : "+v"(AV0), "+v"(AV1), "+v"(C0), "+v"(C1));                 \
    c00 = __builtin_amdgcn_mfma_f32_32x32x16_bf16(AV0, C0, c00, 0, 0, 0);     \
    c10 = __builtin_amdgcn_mfma_f32_32x32x16_bf16(AV1, C0, c10, 0, 0, 0);     \
    c01 = __builtin_amdgcn_mfma_f32_32x32x16_bf16(AV0, C1, c01, 0, 0, 0);     \
    c11 = __builtin_amdgcn_mfma_f32_32x32x16_bf16(AV1, C1, c11, 0, 0, 0);     \
    asm volatile("global_load_dwordx4 %0, %1, %2" : "=v"(AV0)                 \
                 : "v"(vA0), "s"((const void*)(pWg + ((CK) + 2) * CHUNK_STRIDE))); \
    asm volatile("global_load_dwordx4 %0, %1, %2" : "=v"(AV1)                 \
                 : "v"(vA1), "s"((const void*)(pWg + ((CK) + 2) * CHUNK_STRIDE))); \
  }

// Block = (b, 4 output rows) x all 256 oc. 1024 threads = 16 waves =
// 4 waves/SIMD GUARANTEED. Wave w: y-row = w>>2, oc-groups {2(w&3),
// 2(w&3)+1} x 2 n = 4 chains (64 AGPR). R24/R28 evidence: the per-wave
// step window (~1600 cyc) is MFMA wave-block latency (~190 cyc/instr,
// not the 32-cyc throughput slot) — cure is interleaving MORE waves per
// SIMD, which the 8-chain/228-reg config could never fit. ~55 VGPR +
// 64 AGPR = ~119 <= 128 unified (512/4-wave tier).
__global__ __launch_bounds__(1024, 1) void conv_mfma(
    const float* __restrict__ images,
    const unsigned char* __restrict__ W9Tf,
    const float* __restrict__ bias_dense,
    float* __restrict__ out)
{
    int y0 = blockIdx.x * 4;
    if (y0 > 58) y0 = 58;             // tile 15: dup rows 58-61 (identical)
    const int b = blockIdx.y;
    const int t = threadIdx.x;
    const int w = t >> 6;             // 0..15
    const int wq = w & 3;             // oc-pair index
    const int yr = w >> 2;            // y-row 0..3
    const int l = t & 63;
    const int lm = l & 31;            // m-row / n-col within frag
    const int lhi = l >> 5;           // k-half

    __shared__ unsigned char lds[LDS_TOTAL];

    const float* __restrict__ imgb = images + (size_t)b * (IC * RR * CCOLS);

    // ---- stage B: 6 rows -> [krow][octet][x][16B] (conflict-free) ----
    // 1024 threads: t stages x = t&63, octet = t>>6 (all 16), 6 rows.
    {
        const int xs = t & 63;
        const int o = t >> 6;               // octet 0..15, wave-uniform
        const int c0 = o * 8;
        #pragma unroll
        for (int krow = 0; krow < 6; ++krow) {
            const float* __restrict__ p =
                imgb + (size_t)c0 * (RR * CCOLS) + (y0 + krow) * CCOLS + xs;
            unsigned v0, v1, v2, v3;
            v0 = (unsigned)f2bf(p[0])              | ((unsigned)f2bf(p[RR * CCOLS])     << 16);
            v1 = (unsigned)f2bf(p[2 * RR * CCOLS]) | ((unsigned)f2bf(p[3 * RR * CCOLS]) << 16);
            v2 = (unsigned)f2bf(p[4 * RR * CCOLS]) | ((unsigned)f2bf(p[5 * RR * CCOLS]) << 16);
            v3 = (unsigned)f2bf(p[6 * RR * CCOLS]) | ((unsigned)f2bf(p[7 * RR * CCOLS]) << 16);
            *(uint4*)(lds + krow * 16384 + o * 1024 + xs * 16) =
                make_uint4(v0, v1, v2, v3);
        }
    }

    // fixed per-lane 32-bit A v-offsets; runtime SGPR group base pWg
    const int vA0 = (2 * wq + 0) * 1024 + l * 16;
    const int vA1 = (2 * wq + 1) * 1024 + l * 16;
    // B base VGPRs (wave's y-row base). bB1 clamps lm to 29 (in-bounds;
    // clamped lanes' outputs never stored).
    const int lmc = lm > 29 ? 29 : lm;
    const unsigned bB0 = (unsigned)(uintptr_t)(lds + yr * 16384 + lhi * 1024 + lm * 16);
    const unsigned bB1 = (unsigned)(uintptr_t)(lds + yr * 16384 + lhi * 1024 + lmc * 16);

    __syncthreads();   // B staged; all counters drained

    // prologue: A chunks 0,1 (both streams) and B chunk 0 in flight
    const unsigned char* pWg = W9Tf;
    bf16x8 a0S0, a0S1, a1S0, a1S1;
    bf16x8 bX0, bX1, bY0, bY1;
    asm volatile("global_load_dwordx4 %0, %1, %2" : "=v"(a0S0) : "v"(vA0), "s"((const void*)(pWg)));
    asm volatile("global_load_dwordx4 %0, %1, %2" : "=v"(a1S0) : "v"(vA1), "s"((const void*)(pWg)));
    asm volatile("global_load_dwordx4 %0, %1, %2" : "=v"(a0S1) : "v"(vA0), "s"((const void*)(pWg + CHUNK_STRIDE)));
    asm volatile("global_load_dwordx4 %0, %1, %2" : "=v"(a1S1) : "v"(vA1), "s"((const void*)(pWg + CHUNK_STRIDE)));
    asm volatile("ds_read_b128 %0, %1" : "=v"(bX0) : "v"(bB0));
    asm volatile("ds_read_b128 %0, %1 offset:512" : "=v"(bX1) : "v"(bB1));

    // named accumulators c<m><n> (static indexing -> no scratch)
    f32x16 c00 = {}, c01 = {}, c10 = {}, c11 = {};

    // rolled kp loop: 9 groups x 8 chunks; A-slot cycle (2) and B-set
    // cycle (2) both divide 8 -> uniform body across groups.
    // delta to next kp base: +16 (kx step) or +16352 (ky step, g=2,5,8).
    unsigned vB0c = bB0, vB1c = bB1;
    #pragma clang loop unroll(disable)
    for (int g = 0; g < 9; ++g) {
        const unsigned delta = ((0x124u >> g) & 1u) ? 16352u : 16u;
        const unsigned vB0n = vB0c + delta;
        const unsigned vB1n = vB1c + delta;
        KSTEP_L(0, a0S0, a1S0, bX0, bX1, bY0, bY1, vB0c, vB1c, 1 * 2048)
        KSTEP_L(1, a0S1, a1S1, bY0, bY1, bX0, bX1, vB0c, vB1c, 2 * 2048)
        KSTEP_L(2, a0S0, a1S0, bX0, bX1, bY0, bY1, vB0c, vB1c, 3 * 2048)
        KSTEP_L(3, a0S1, a1S1, bY0, bY1, bX0, bX1, vB0c, vB1c, 4 * 2048)
        KSTEP_L(4, a0S0, a1S0, bX0, bX1, bY0, bY1, vB0c, vB1c, 5 * 2048)
        KSTEP_L(5, a0S1, a1S1, bY0, bY1, bX0, bX1, vB0c, vB1c, 6 * 2048)
        KSTEP_L(6, a0S0, a1S0, bX0, bX1, bY0, bY1, vB0c, vB1c, 7 * 2048)
        KSTEP_L(7, a0S1, a1S1, bY0, bY1, bX0, bX1, vB0n, vB1n, 0)
        vB0c = vB0n; vB1c = vB1n;
        pWg += 8 * CHUNK_STRIDE;
    }

    // drain ALL in-flight junk prefetches BEFORE the epilogue, with every
    // asm target register tied (R27 liveness lesson).
    asm volatile("s_waitcnt vmcnt(0) lgkmcnt(0)"
                 : "+v"(a0S0), "+v"(a0S1), "+v"(a1S0), "+v"(a1S1),
                   "+v"(bX0), "+v"(bX1), "+v"(bY0), "+v"(bY1));

    // ---- epilogue: bias + store ----
    // C/D 32x32: col = lane&31, row = (reg&3) + 8*(reg>>2) + 4*(lane>>5)
    const int yb = y0 + yr;
    #pragma unroll
    for (int m = 0; m < 2; ++m) {
        const int ocw = (2 * wq + m) * 32;
        const f32x16 d0 = m ? c10 : c00;   // [n0]
        const f32x16 d1 = m ? c11 : c01;   // [n1]
        #pragma unroll
        for (int r = 0; r < 16; ++r) {
            const int oc = ocw + (r & 3) + 8 * (r >> 2) + 4 * lhi;
            const float bv = bias_dense[oc];
            const size_t ob = (((size_t)b * OC + oc) * HO + yb) * WO;
            out[ob + lm] = d0[r] + bv;               // x = lm < 62 always
            if (lm < 30)
                out[ob + 32 + lm] = d1[r] + bv;      // x = 32+lm, clip at 62
        }
    }
}

extern "C" void kernel_launch(void* const* d_in, const int* in_sizes, int n_in,
                              void* d_out, int out_size, void* d_ws, size_t ws_size,
                              hipStream_t stream) {
    const float* images             = (const float*)d_in[0];
    const float* weight_value       = (const float*)d_in[1];
    const int*   image_weight_index = (const int*)d_in[2];
    const int*   filter_lengths     = (const int*)d_in[3];
    const int*   start_points       = (const int*)d_in[4];
    const int*   bias_index         = (const int*)d_in[5];
    const float* bias_value         = (const float*)d_in[6];
    float* out = (float*)d_out;

    unsigned char* W9Tf = (unsigned char*)d_ws;
    float* bias_dense = (float*)((char*)d_ws + W9T_BYTES + W9T_PAD);

    // zero weights + tail pad (junk A-prefetches land in the pad)
    hipMemsetAsync(d_ws, 0, W9T_BYTES + W9T_PAD, stream);
    prep_weights<<<OC + 1, 256, 0, stream>>>(weight_value, image_weight_index,
                                             filter_lengths, start_points, W9Tf,
                                             bias_index, bias_value, bias_dense,
                                             in_sizes[5]);

    dim3 grid(16, NB);
    conv_mfma<<<grid, 1024, 0, stream>>>(images, W9Tf, bias_dense, out);
}

// Round 30
// 56.387 us; speedup vs baseline: 1.1311x; 1.1311x over previous
//
#include <hip/hip_runtime.h>
#include <stdint.h>

#define IC 128
#define OC 256
#define RR 64
#define CCOLS 64
#define HO 62
#define WO 62
#define NB 16

// Fragment-major dense bf16 weights: W9Tf[chunk][g][lane][16B],
// chunk = kp*8+ck (72), g = oc>>5 (8), lane = (oc&31)+32*khalf.
#define W9T_BYTES (9 * OC * IC * 2)   // 589824
#define W9T_PAD   131072              // zero pad: junk tail A-loads land here
#define CHUNK_STRIDE 8192
// B LDS layout: [krow 6][octet 16][x 64][16B] = 98304 B + 4 KB pad for the
// rolled loop's junk tail B-reads (max junk read byte = 100336 < 102400).
#define LDS_TOTAL 102400

typedef __bf16 bf16x8 __attribute__((ext_vector_type(8)));
typedef float f32x16 __attribute__((ext_vector_type(16)));

__device__ __forceinline__ unsigned short f2bf(float f) {
    unsigned u = __builtin_bit_cast(unsigned, f);
    u += 0x7FFFu + ((u >> 16) & 1u);   // round-to-nearest-even
    return (unsigned short)(u >> 16);
}

// prep: blocks 0..OC-1 scatter weights; block OC densifies the bias.
__global__ void prep_weights(const float* __restrict__ wv,
                             const int* __restrict__ iwi,
                             const int* __restrict__ flen,
                             const int* __restrict__ sp,
                             unsigned char* __restrict__ W9Tf,
                             const int* __restrict__ bias_index,
                             const float* __restrict__ bias_value,
                             float* __restrict__ bias_dense, int nbias) {
    if (blockIdx.x == OC) {
        int t = threadIdx.x;
        if (t < OC) bias_dense[t] = 0.f;
        __syncthreads();
        if (t < nbias) atomicAdd(&bias_dense[bias_index[t]], bias_value[t]);
        return;
    }
    const int oc = blockIdx.x;
    const int s = sp[oc];
    const int n = flen[oc];
    const int g = oc >> 5;
    for (int t = threadIdx.x; t < n; t += blockDim.x) {
        const int ix = iwi[s + t];          // c*4096 + ky*64 + kx
        const int c = ix >> 12;
        const int rem = ix & 4095;
        const int ky = rem >> 6, kx = rem & 63;
        const int kp = ky * 3 + kx;
        const int ck = c >> 4;
        const int khalf = (c >> 3) & 1;
        const int lane = (oc & 31) + (khalf << 5);
        const size_t off = (size_t)(kp * 8 + ck) * CHUNK_STRIDE +
                           g * 1024 + lane * 16 + (c & 7) * 2;
        *(unsigned short*)(W9Tf + off) = f2bf(wv[s + t]);
    }
}

// One K-chunk step inside the rolled kp-group loop. CK literal 0..7; B
// chunk base carried in VGPRs (PB0/PB1) with immediate per-chunk offsets;
// A base = loop SGPR pointer + literal offset. Uniform vmcnt(6)/lgkmcnt(4);
// trailing junk prefetches (last group) read the zero pad (A) / LDS pad (B)
// and are drained AFTER the loop with all target regs tied (liveness!).
#define KSTEP_L(CK, AV0, AV1, C00, C01, C10, C11, N00, N01, N10, N11, PB0, PB1, POFF) \
  {                                                                           \
    asm volatile("ds_read_b128 %0, %1 offset:%c2" : "=v"(N00) : "v"(PB0), "i"(POFF)); \
    asm volatile("ds_read_b128 %0, %1 offset:%c2" : "=v"(N01) : "v"(PB1), "i"((POFF) + 512)); \
    asm volatile("ds_read_b128 %0, %1 offset:%c2" : "=v"(N10) : "v"(PB0), "i"((POFF) + 16384)); \
    asm volatile("ds_read_b128 %0, %1 offset:%c2" : "=v"(N11) : "v"(PB1), "i"((POFF) + 16896)); \
    asm volatile("s_waitcnt vmcnt(6) lgkmcnt(4)"                              \
                 : "+v"(AV0), "+v"(AV1), "+v"(C00), "+v"(C01), "+v"(C10), "+v"(C11)); \
    c000 = __builtin_amdgcn_mfma_f32_32x32x16_bf16(AV0, C00, c000, 0, 0, 0);  \
    c100 = __builtin_amdgcn_mfma_f32_32x32x16_bf16(AV1, C00, c100, 0, 0, 0);  \
    c001 = __builtin_amdgcn_mfma_f32_32x32x16_bf16(AV0, C01, c001, 0, 0, 0);  \
    c101 = __builtin_amdgcn_mfma_f32_32x32x16_bf16(AV1, C01, c101, 0, 0, 0);  \
    c010 = __builtin_amdgcn_mfma_f32_32x32x16_bf16(AV0, C10, c010, 0, 0, 0);  \
    c110 = __builtin_amdgcn_mfma_f32_32x32x16_bf16(AV1, C10, c110, 0, 0, 0);  \
    c011 = __builtin_amdgcn_mfma_f32_32x32x16_bf16(AV0, C11, c011, 0, 0, 0);  \
    c111 = __builtin_amdgcn_mfma_f32_32x32x16_bf16(AV1, C11, c111, 0, 0, 0);  \
    asm volatile("global_load_dwordx4 %0, %1, %2" : "=v"(AV0)                 \
                 : "v"(vA0), "s"((const void*)(pWg + ((CK) + 4) * CHUNK_STRIDE))); \
    asm volatile("global_load_dwordx4 %0, %1, %2" : "=v"(AV1)                 \
                 : "v"(vA1), "s"((const void*)(pWg + ((CK) + 4) * CHUNK_STRIDE))); \
  }

// Block = (b, 4 output rows) x all 256 oc. 512 threads = 8 waves.
// Waves 0-3: y-pair 0; waves 4-7: y-pair 1. Wave: 2 oc x 2 y x 2 n =
// 8 chains/step. CHAMPION CONFIG (R28): conflict-free B layout, opaque
// 4-deep A pipeline + 1-deep B pipeline with counted waits, no in-loop
// VALU, rolled 9x8 K-loop, no setprio (null in lockstep regime, R26).
// R29's 16-wave/4-chain variant regressed (TA-bound: memory-op rate per
// wave constant while MFMA work halved) — this is the measured optimum:
// conv ~46us = 3.1x the 15us MFMA-pipe floor; all pipes <= 35%.
__global__ __launch_bounds__(512, 2) void conv_mfma(
    const float* __restrict__ images,
    const unsigned char* __restrict__ W9Tf,
    const float* __restrict__ bias_dense,
    float* __restrict__ out)
{
    int y0 = blockIdx.x * 4;
    if (y0 > 58) y0 = 58;             // tile 15: dup rows 58-61 (identical)
    const int b = blockIdx.y;
    const int t = threadIdx.x;
    const int w = t >> 6;             // 0..7
    const int wq = w & 3;             // oc-pair index
    const int ypg = w >> 2;           // y-pair index 0/1
    const int l = t & 63;
    const int lm = l & 31;            // m-row / n-col within frag
    const int lhi = l >> 5;           // k-half

    __shared__ unsigned char lds[LDS_TOTAL];

    const float* __restrict__ imgb = images + (size_t)b * (IC * RR * CCOLS);

    // ---- stage B: 6 rows -> [krow][octet][x][16B] (conflict-free) ----
    {
        const int xs = t & 63;
        const int og = t >> 6;              // 0..7, wave-uniform
        #pragma unroll
        for (int krow = 0; krow < 6; ++krow) {
            #pragma unroll
            for (int h = 0; h < 2; ++h) {
                const int o = og + 8 * h;           // octet 0..15
                const int c0 = o * 8;
                const float* __restrict__ p =
                    imgb + (size_t)c0 * (RR * CCOLS) + (y0 + krow) * CCOLS + xs;
                unsigned v0, v1, v2, v3;
                v0 = (unsigned)f2bf(p[0])              | ((unsigned)f2bf(p[RR * CCOLS])     << 16);
                v1 = (unsigned)f2bf(p[2 * RR * CCOLS]) | ((unsigned)f2bf(p[3 * RR * CCOLS]) << 16);
                v2 = (unsigned)f2bf(p[4 * RR * CCOLS]) | ((unsigned)f2bf(p[5 * RR * CCOLS]) << 16);
                v3 = (unsigned)f2bf(p[6 * RR * CCOLS]) | ((unsigned)f2bf(p[7 * RR * CCOLS]) << 16);
                *(uint4*)(lds + krow * 16384 + o * 1024 + xs * 16) =
                    make_uint4(v0, v1, v2, v3);
            }
        }
    }

    // fixed per-lane 32-bit A v-offsets; runtime SGPR group base pWg
    const int vA0 = (2 * wq + 0) * 1024 + l * 16;
    const int vA1 = (2 * wq + 1) * 1024 + l * 16;
    // B base VGPRs (wave's y-pair base). bB1 clamps lm to 29 (in-bounds;
    // clamped lanes' outputs never stored).
    const int lmc = lm > 29 ? 29 : lm;
    const unsigned bB0 = (unsigned)(uintptr_t)(lds + ypg * 32768 + lhi * 1024 + lm * 16);
    const unsigned bB1 = (unsigned)(uintptr_t)(lds + ypg * 32768 + lhi * 1024 + lmc * 16);

    __syncthreads();   // B staged; all counters drained

    // prologue: A chunks 0..3 (both streams) and B chunk 0 in flight
    const unsigned char* pWg = W9Tf;
    bf16x8 a0S0, a0S1, a0S2, a0S3, a1S0, a1S1, a1S2, a1S3;
    bf16x8 bX00, bX01, bX10, bX11, bY00, bY01, bY10, bY11;
    asm volatile("global_load_dwordx4 %0, %1, %2" : "=v"(a0S0) : "v"(vA0), "s"((const void*)(pWg)));
    asm volatile("global_load_dwordx4 %0, %1, %2" : "=v"(a1S0) : "v"(vA1), "s"((const void*)(pWg)));
    asm volatile("global_load_dwordx4 %0, %1, %2" : "=v"(a0S1) : "v"(vA0), "s"((const void*)(pWg + CHUNK_STRIDE)));
    asm volatile("global_load_dwordx4 %0, %1, %2" : "=v"(a1S1) : "v"(vA1), "s"((const void*)(pWg + CHUNK_STRIDE)));
    asm volatile("global_load_dwordx4 %0, %1, %2" : "=v"(a0S2) : "v"(vA0), "s"((const void*)(pWg + 2 * CHUNK_STRIDE)));
    asm volatile("global_load_dwordx4 %0, %1, %2" : "=v"(a1S2) : "v"(vA1), "s"((const void*)(pWg + 2 * CHUNK_STRIDE)));
    asm volatile("global_load_dwordx4 %0, %1, %2" : "=v"(a0S3) : "v"(vA0), "s"((const void*)(pWg + 3 * CHUNK_STRIDE)));
    asm volatile("global_load_dwordx4 %0, %1, %2" : "=v"(a1S3) : "v"(vA1), "s"((const void*)(pWg + 3 * CHUNK_STRIDE)));
    asm volatile("ds_read_b128 %0, %1" : "=v"(bX00) : "v"(bB0));
    asm volatile("ds_read_b128 %0, %1 offset:512" : "=v"(bX01) : "v"(bB1));
    asm volatile("ds_read_b128 %0, %1 offset:16384" : "=v"(bX10) : "v"(bB0));
    asm volatile("ds_read_b128 %0, %1 offset:16896" : "=v"(bX11) : "v"(bB1));

    // named accumulators c<m><yy><n> (static indexing -> no scratch)
    f32x16 c000 = {}, c001 = {}, c010 = {}, c011 = {};
    f32x16 c100 = {}, c101 = {}, c110 = {}, c111 = {};

    // rolled kp loop: 9 groups x 8 chunks; body stays I-cache resident.
    // delta to next kp base: +16 (kx step) or +16352 (ky step, g=2,5,8).
    unsigned vB0c = bB0, vB1c = bB1;
    #pragma clang loop unroll(disable)
    for (int g = 0; g < 9; ++g) {
        const unsigned delta = ((0x124u >> g) & 1u) ? 16352u : 16u;
        const unsigned vB0n = vB0c + delta;
        const unsigned vB1n = vB1c + delta;
        KSTEP_L(0, a0S0, a1S0, bX00, bX01, bX10, bX11, bY00, bY01, bY10, bY11, vB0c, vB1c, 1 * 2048)
        KSTEP_L(1, a0S1, a1S1, bY00, bY01, bY10, bY11, bX00, bX01, bX10, bX11, vB0c, vB1c, 2 * 2048)
        KSTEP_L(2, a0S2, a1S2, bX00, bX01, bX10, bX11, bY00, bY01, bY10, bY11, vB0c, vB1c, 3 * 2048)
        KSTEP_L(3, a0S3, a1S3, bY00, bY01, bY10, bY11, bX00, bX01, bX10, bX11, vB0c, vB1c, 4 * 2048)
        KSTEP_L(4, a0S0, a1S0, bX00, bX01, bX10, bX11, bY00, bY01, bY10, bY11, vB0c, vB1c, 5 * 2048)
        KSTEP_L(5, a0S1, a1S1, bY00, bY01, bY10, bY11, bX00, bX01, bX10, bX11, vB0c, vB1c, 6 * 2048)
        KSTEP_L(6, a0S2, a1S2, bX00, bX01, bX10, bX11, bY00, bY01, bY10, bY11, vB0c, vB1c, 7 * 2048)
        KSTEP_L(7, a0S3, a1S3, bY00, bY01, bY10, bY11, bX00, bX01, bX10, bX11, vB0n, vB1n, 0)
        vB0c = vB0n; vB1c = vB1n;
        pWg += 8 * CHUNK_STRIDE;
    }

    // drain ALL in-flight junk prefetches BEFORE the epilogue, with every
    // asm target register tied (R27 liveness lesson).
    asm volatile("s_waitcnt vmcnt(0) lgkmcnt(0)"
                 : "+v"(a0S0), "+v"(a0S1), "+v"(a0S2), "+v"(a0S3),
                   "+v"(a1S0), "+v"(a1S1), "+v"(a1S2), "+v"(a1S3),
                   "+v"(bX00), "+v"(bX01), "+v"(bX10), "+v"(bX11),
                   "+v"(bY00), "+v"(bY01), "+v"(bY10), "+v"(bY11));

    // ---- epilogue: bias + store ----
    // C/D 32x32: col = lane&31, row = (reg&3) + 8*(reg>>2) + 4*(lane>>5)
    const int yb = y0 + 2 * ypg;
    #pragma unroll
    for (int m = 0; m < 2; ++m) {
        const int ocw = (2 * wq + m) * 32;
        const f32x16 d00 = m ? c100 : c000;   // [yb][n0]
        const f32x16 d01 = m ? c101 : c001;   // [yb][n1]
        const f32x16 d10 = m ? c110 : c010;   // [yb+1][n0]
        const f32x16 d11 = m ? c111 : c011;   // [yb+1][n1]
        #pragma unroll
        for (int r = 0; r < 16; ++r) {
            const int oc = ocw + (r & 3) + 8 * (r >> 2) + 4 * lhi;
            const float bv = bias_dense[oc];
            const size_t ob0 = (((size_t)b * OC + oc) * HO + yb) * WO;
            out[ob0 + lm] = d00[r] + bv;             // x = lm < 62 always
            if (lm < 30)
                out[ob0 + 32 + lm] = d01[r] + bv;    // x = 32+lm, clip at 62
            const size_t ob1 = ob0 + WO;             // row yb+1
            out[ob1 + lm] = d10[r] + bv;
            if (lm < 30)
                out[ob1 + 32 + lm] = d11[r] + bv;
        }
    }
}

extern "C" void kernel_launch(void* const* d_in, const int* in_sizes, int n_in,
                              void* d_out, int out_size, void* d_ws, size_t ws_size,
                              hipStream_t stream) {
    const float* images             = (const float*)d_in[0];
    const float* weight_value       = (const float*)d_in[1];
    const int*   image_weight_index = (const int*)d_in[2];
    const int*   filter_lengths     = (const int*)d_in[3];
    const int*   start_points       = (const int*)d_in[4];
    const int*   bias_index         = (const int*)d_in[5];
    const float* bias_value         = (const float*)d_in[6];
    float* out = (float*)d_out;

    unsigned char* W9Tf = (unsigned char*)d_ws;
    float* bias_dense = (float*)((char*)d_ws + W9T_BYTES + W9T_PAD);

    // zero weights + tail pad (junk A-prefetches of the rolled loop land
    // in the pad; initialized memory, no OOB)
    hipMemsetAsync(d_ws, 0, W9T_BYTES + W9T_PAD, stream);
    prep_weights<<<OC + 1, 256, 0, stream>>>(weight_value, image_weight_index,
                                             filter_lengths, start_points, W9Tf,
                                             bias_index, bias_value, bias_dense,
                                             in_sizes[5]);

    dim3 grid(16, NB);
    conv_mfma<<<grid, 512, 0, stream>>>(images, W9Tf, bias_dense, out);
}